// Round 21
// baseline (45.911 us; speedup 1.0000x reference)
//
#include <hip/hip_runtime.h>
#include <stdint.h>

// Reference: pos += fl32(vel*dt); vel += fl32(fl32(-9.81)*fl32(0.01)); record pos.
// Exact emulation of the f32 scan via piecewise-constant-increment runs.
// r21: TWO dispatches for observability + specialization. prep (1 wave):
// direct-64 + integer closed-form staircase (~36 links, no ballots) + ballot
// fallback + run-chain (~5 single-window ballots); publishes tables to d_ws.
// fill (1024 blocks): pure consumer — loads tables to LDS, r20 fast-mode
// loops + nt stores, ZERO per-block prep. r6-r11's two-launch lost because
// prep was ~30us of ballots; integer prep is ~3-10us. rocprof now reports
// prep and fill dur SEPARATELY (fused hid this split for 8 rounds).

static constexpr long long NSTEPS = 10000000LL;  // output rows
static constexpr long long NPOLY  = 1000000LL;   // polynomial cutover (even)
static constexpr long long NS     = 8000000LL;   // model/run cutover (even)
static constexpr long long KDIR   = 64;          // direct f32 steps
static constexpr int SEGCAP = 384;
static constexpr int RUNCAP = 96;

typedef float f4_native __attribute__((ext_vector_type(4)));

__device__ __forceinline__ bool same_binade_f32(float a, float b) {
    return (((__float_as_uint(a) ^ __float_as_uint(b)) & 0xFF800000u) == 0u);
}
__device__ __forceinline__ unsigned expfield(float v) {
    return (__float_as_uint(v) >> 23) & 0xFFu;
}
__device__ __forceinline__ float pow2f(int e) {
    return __uint_as_float((unsigned)(e + 127) << 23);
}
__device__ __forceinline__ double pow2d(int e) {
    return __longlong_as_double(((long long)(e + 1023)) << 52);
}
__device__ __forceinline__ void nt_store(float4* p, float4 v) {
    f4_native nv;
    nv.x = v.x; nv.y = v.y; nv.z = v.z; nv.w = v.w;
    __builtin_nontemporal_store(nv, (f4_native*)p);
}

// ===================== PREP: one wave builds all tables ======================
__global__ __launch_bounds__(64) void prep(
        const float* __restrict__ pos0, const float* __restrict__ vel0,
        int* __restrict__ counts,
        int* __restrict__ g_m, double* __restrict__ g_V,
        double* __restrict__ g_c, double* __restrict__ g_P,
        int* __restrict__ g_rn, double* __restrict__ g_rp,
        double* __restrict__ g_ri)
{
    __shared__ int    s_m[SEGCAP + 1];
    __shared__ double s_V[SEGCAP], s_c[SEGCAP], s_P[SEGCAP];
    __shared__ int    r_n[RUNCAP];
    __shared__ double r_p[RUNCAP], r_i[RUNCAP];
    __shared__ int    s_nseg, s_bad, s_nrun;
    __shared__ long long s_mstop;
    __shared__ double s_v64, s_p64;

    const int lane = threadIdx.x;
    const float dtf  = 0.01f;
    const float gdtf = __fmul_rn(-9.81f, dtf);
    const double dtd = (double)dtf, gcd = (double)gdtf;
    const double p0y = (double)pos0[1], v0y = (double)vel0[1];
    const long long mstop = NSTEPS;

    // ---- Phase A (lane 0): direct-64 + INTEGER closed-form staircase ----
    if (lane == 0) {
        s_nrun = 0;
        double V = v0y, P = p0y;
        for (int t = 0; t < (int)KDIR; ++t) {     // exact by definition
            const float vf = (float)V;
            P += dtd * V;
            V = (double)__fadd_rn(vf, gdtf);
        }
        s_v64 = V; s_p64 = P;

        bool bad = false;
        long long m = KDIR;
        int nseg = 0;
        while (m < mstop) {
            if (nseg >= SEGCAP - 2) { bad = true; break; }
            const float vf = (float)V;
            if ((double)vf != V || !(vf < 0.0f)) { bad = true; break; }
            const unsigned ef = expfield(vf);
            if (ef == 0u || ef == 0xFFu) { bad = true; break; }
            const int k = (int)ef - 126;            // |V| in [2^(k-1), 2^k)
            const double ulp     = pow2d(k - 24);
            const double inv_ulp = pow2d(24 - k);
            const double g = -V * inv_ulp;          // exact integer in [2^23,2^24)
            const double q = -gcd * inv_ulp;        // exact dyadic, > 0
            const double fq = floor(q);
            const long long rem = mstop - m;

            if (q - fq == 0.5) {                    // tie binade: 1-step links
                const float vb = __fadd_rn(vf, gdtf);
                const double cb = (double)vb - V;
                s_m[nseg] = (int)m; s_V[nseg] = V; s_c[nseg] = cb; s_P[nseg] = P; ++nseg;
                P += dtd * V; V += cb; m += 1;
                continue;
            }
            const double cg = floor(q + 0.5);       // round(q), integer >= 0
            if (!(cg > 0.0)) { bad = true; break; }
            const double c = -cg * ulp;             // exact f64 increment

            // T = max t>=1 with pre-round g+(t-1)*cg+q < 2^24 (stay in binade)
            const double lim = 16777216.0;
            float t0f = __fdividef((float)(lim - g - q), (float)cg);
            long long T = (long long)t0f + 1;
            if (T > rem) T = rem;
            if (T < 0) T = 0;
            for (int f = 0; f < 4 && T > 0 && !(g + (double)(T - 1) * cg + q < lim); ++f) --T;
            for (int f = 0; f < 4 && T < rem && (g + (double)T * cg + q < lim); ++f) ++T;
            if (T > rem) T = rem;

            if (T > 0) {                            // main segment
                s_m[nseg] = (int)m; s_V[nseg] = V; s_c[nseg] = c; s_P[nseg] = P; ++nseg;
                P += dtd * ((double)T * V + c * ((double)T * (double)(T - 1) * 0.5));
                V += (double)T * c;                 // exact dyadics
                m += T;
                if (m >= mstop) break;
            }
            // boundary step: direct f32 (exact regardless of binade change)
            const float vf2 = (float)V;
            if ((double)vf2 != V) { bad = true; break; }
            const float vb = __fadd_rn(vf2, gdtf);
            const double cb = (double)vb - V;
            s_m[nseg] = (int)m; s_V[nseg] = V; s_c[nseg] = cb; s_P[nseg] = P; ++nseg;
            P += dtd * V; V += cb; m += 1;
        }
        bad = bad || (m < mstop);
        s_bad = bad ? 1 : 0;
        s_nseg = nseg;
        s_mstop = m;
        s_m[nseg] = 0x7fffffff;                     // sentinel
    }
    __syncthreads();

    // ---- Phase C: fallback — ballot staircase (visible in prep dur) ----
    if (s_bad) {
        double V = s_v64, P = s_p64;
        long long m = KDIR;
        int nseg = 0;
        while (m < mstop && nseg < SEGCAP) {
            const float vf  = (float)V;
            const float vn1 = __fadd_rn(vf, gdtf);
            const double c  = (double)vn1 - V;
            const long long rem = mstop - m;
            long long Lb = rem;
            const float cf = (float)c;
            const unsigned ef = expfield(vf);
            if (vf == 0.0f || ef == 0u) {
                Lb = 64;
            } else if (cf != 0.0f) {
                const int k = (int)ef - 126;
                float s = vf < 0.0f ? -1.0f : 1.0f;
                float B = ((vf < 0.0f) == (cf < 0.0f)) ? s * pow2f(k) : s * pow2f(k - 1);
                float r = __fdividef(B - vf, cf);
                if (r >= 0.0f && r < 4.0e9f) Lb = (long long)r + 1;
            }
            long long Lhi = Lb + 2;
            if (Lhi > rem) Lhi = rem;
            if (Lhi < 1) Lhi = 1;

            long long L = 1;
            {
                const long long candL = Lhi - 63 + (long long)lane;
                bool valid = false;
                if (candL >= 1) {
                    const double ve = V + (double)(candL - 1) * c;
                    const float vef = (float)ve;
                    const float vn2 = __fadd_rn(vef, gdtf);
                    valid = ((double)vef == ve)
                         && same_binade_f32(vef, vf)
                         && ((double)vn2 - ve == c);
                }
                const unsigned long long msk = __ballot(valid);
                if (msk) L = Lhi - 63 + (long long)(63 - __clzll(msk));
            }
            if (L < 1) L = 1;
            if (L > rem) L = rem;

            if (lane == 0) { s_m[nseg] = (int)m; s_V[nseg] = V; s_c[nseg] = c; s_P[nseg] = P; }
            ++nseg;
            P += dtd * ((double)L * V + c * ((double)L * (double)(L - 1) * 0.5));
            V += (double)L * c;
            m += L;
        }
        if (lane == 0) { s_nseg = nseg; s_mstop = m; s_m[nseg] = 0x7fffffff; }
    }
    __syncthreads();

    // ---- Phase D: pos run-chain from NS (single-window ballots) ----
    if (s_mstop >= NS && s_nseg > 0) {
        const int nseg = s_nseg;
        const long long mbuilt = s_mstop;
        int lo = 0, hi = nseg - 1;
        while (lo < hi) { int mid = (lo + hi + 1) >> 1;
                          if ((long long)s_m[mid] <= NS) lo = mid; else hi = mid - 1; }
        int jj = lo;
        const double t0 = (double)(NS - s_m[jj]);
        double vel = s_V[jj] + t0 * s_c[jj];
        double P2  = s_P[jj] + dtd * (t0 * s_V[jj] + s_c[jj] * (t0 * (t0 - 1.0) * 0.5));
        double pos = (double)(float)P2;
        long long n = NS;
        int nrun = 0;
        long long nend = NSTEPS - 1;
        if (nend > mbuilt) nend = mbuilt;
        while (n < nend && nrun < RUNCAP) {
            while (s_m[jj + 1] <= (int)n) ++jj;
            const double cv = s_c[jj];
            long long Lcap = (long long)s_m[jj + 1] - n;
            if (Lcap > mbuilt - n) Lcap = mbuilt - n;
            const long long rem = (NSTEPS - 1) - n;
            if (Lcap > rem) Lcap = rem;

            const float pf = (float)pos;
            const float vf2 = (float)vel;
            const float dstep = __fmul_rn(vf2, dtf);
            const float pn1 = __fadd_rn(pf, dstep);
            const double inc = (double)pn1 - pos;

            long long La = Lcap, Lc = Lcap;
            const float incf = (float)inc;
            const unsigned efp = expfield(pf);
            if (pf == 0.0f || efp == 0u) {
                La = 64;
            } else if (incf != 0.0f) {
                const int k = (int)efp - 126;
                float s = pf < 0.0f ? -1.0f : 1.0f;
                float B = ((pf < 0.0f) == (incf < 0.0f)) ? s * pow2f(k) : s * pow2f(k - 1);
                float r = __fdividef(B - pf, incf);
                if (r >= 0.0f && r < 4.0e9f) { La = (long long)r - 1; if (La < 0) La = 0; }
            }
            const double dd = cv * dtd;
            if (dd != 0.0 && pf != 0.0f && efp != 0u) {
                const int k = (int)efp - 126;
                if (k - 24 > -126) {
                    const float ulpf = pow2f(k - 24);
                    const double d0 = (double)dstep;
                    const double T = inc + (dd < 0.0 ? -0.5 : 0.5) * (double)ulpf;
                    float r = __fdividef((float)(T - d0), (float)dd);
                    if (r >= 0.0f && r < 4.0e9f) { Lc = (long long)r + 2; if (Lc < 1) Lc = 1; }
                }
            }
            long long Lhi = La < Lc ? La : Lc;
            Lhi += 3;
            if (Lhi > Lcap) Lhi = Lcap;
            if (Lhi < 1) Lhi = 1;

            long long L = 1;
            {
                const long long candL = Lhi - 63 + (long long)lane;
                bool valid = false;
                if (candL >= 1) {
                    const double pe = pos + (double)(candL - 1) * inc;
                    const double ve = vel + (double)(candL - 1) * cv;
                    const float pef = (float)pe;
                    const float vef = (float)ve;
                    const float d2  = __fmul_rn(vef, dtf);
                    const float pn2 = __fadd_rn(pef, d2);
                    valid = ((double)pef == pe)
                         && same_binade_f32(pef, pf)
                         && ((double)vef == ve)
                         && ((double)pn2 - pe == inc);
                }
                const unsigned long long msk = __ballot(valid);
                if (msk) L = Lhi - 63 + (long long)(63 - __clzll(msk));
            }
            if (L < 1) L = 1;
            if (L > Lcap) L = Lcap;
            if (L < 1) L = 1;

            if (lane == 0) { r_n[nrun] = (int)n; r_p[nrun] = pos; r_i[nrun] = inc; }
            ++nrun;
            pos += (double)L * inc;
            vel += (double)L * cv;
            n += L;
        }
        if (lane == 0) s_nrun = nrun;
    }
    __syncthreads();

    // ---- Publish tables (lane-parallel) ----
    const int nseg = s_nseg, nrun = s_nrun;
    for (int i = lane; i <= nseg; i += 64) {
        g_m[i] = s_m[i];
        if (i < nseg) { g_V[i] = s_V[i]; g_c[i] = s_c[i]; g_P[i] = s_P[i]; }
    }
    for (int i = lane; i < nrun; i += 64) {
        g_rn[i] = r_n[i]; g_rp[i] = r_p[i]; g_ri[i] = r_i[i];
    }
    if (lane == 0) { counts[0] = nseg; counts[1] = nrun; }
}

// ===================== FILL: pure table consumer =============================
__global__ __launch_bounds__(256, 4) void fill(
        const float* __restrict__ pos0, const float* __restrict__ vel0,
        const int* __restrict__ counts,
        const int* __restrict__ g_m, const double* __restrict__ g_V,
        const double* __restrict__ g_c, const double* __restrict__ g_P,
        const int* __restrict__ g_rn, const double* __restrict__ g_rp,
        const double* __restrict__ g_ri,
        float4* __restrict__ out, long long npairs)
{
    __shared__ int   s_m[SEGCAP + 1];
    __shared__ float s_Vf[SEGCAP], s_cdt[SEGCAP], s_Pf[SEGCAP];
    __shared__ int   r_n[RUNCAP];
    __shared__ float r_pf[RUNCAP], r_if[RUNCAP];

    const int tid = threadIdx.x;
    const long long per = (npairs + (long long)gridDim.x - 1) / (long long)gridDim.x;
    const long long i0 = (long long)blockIdx.x * per;
    long long i1 = i0 + per; if (i1 > npairs) i1 = npairs;
    if (i0 >= npairs) return;
    const long long row0 = 2 * i0;
    const long long row1 = 2 * i1;

    const float dtf  = 0.01f;
    const float gdtf = __fmul_rn(-9.81f, dtf);
    const double dtd = (double)dtf;

    const int nseg = counts[0];
    const int nrun = counts[1];
    // Load tables to LDS (f32 mirrors; ~50 segs + ~5 runs real).
    for (int i = tid; i <= nseg && i <= SEGCAP; i += 256) s_m[i] = g_m[i];
    for (int i = tid; i < nseg && i < SEGCAP; i += 256) {
        s_Vf[i]  = (float)g_V[i];
        s_cdt[i] = (float)(dtd * g_c[i]);
        s_Pf[i]  = (float)g_P[i];
    }
    for (int i = tid; i < nrun && i < RUNCAP; i += 256) {
        r_n[i]  = g_rn[i];
        r_pf[i] = (float)g_rp[i];
        r_if[i] = (float)g_ri[i];
    }
    __syncthreads();

    const float pxf = pos0[0];
    const float cxf = __fmul_rn(vel0[0], dtf);
    const float pyf = pos0[1];
    const float vyf = vel0[1];
    const float q2f = (float)((double)dtf * (double)gdtf);   // dt*gc

    const long long ii = i0 + tid;
    if (ii >= i1) return;

    // Classify block: 0 poly, 1 single-segment, 2 single-run, 3 general.
    int mode = 3, jf = 0, rf = 0;
    if (row1 <= NPOLY) {
        mode = 0;
    } else if (row0 >= NS && nrun > 0) {
        int rlo = 0, rhi = nrun - 1;
        const int t0 = (int)row0;
        while (rlo < rhi) { int mid = (rlo + rhi + 1) >> 1; if (r_n[mid] <= t0) rlo = mid; else rhi = mid - 1; }
        rf = rlo;
        if (rf + 1 >= nrun || (long long)r_n[rf + 1] >= row1) mode = 2;
    } else if (row0 >= NPOLY && row1 <= NS && nseg > 0) {
        int lo = 0, hi = nseg - 1;
        const int t0 = (int)row0;
        while (lo < hi) { int mid = (lo + hi + 1) >> 1; if (s_m[mid] <= t0) lo = mid; else hi = mid - 1; }
        jf = lo;
        if ((long long)s_m[jf + 1] >= row1) mode = 1;
    }

    if (mode == 0) {            // y = A + B*m + C*m^2 (registers only)
        const float C = 0.5f * q2f;
        const float B = dtf * vyf - C;
        const float A = pyf;
        for (long long i = ii; i < i1; i += blockDim.x) {
            const float mf0 = (float)(2 * i), mf1 = mf0 + 1.0f;
            float4 o;
            o.x = fmaf(mf0, cxf, pxf);
            o.z = fmaf(mf1, cxf, pxf);
            o.y = fmaf(mf0, fmaf(mf0, C, B), A);
            o.w = fmaf(mf1, fmaf(mf1, C, B), A);
            nt_store(&out[i], o);
        }
    } else if (mode == 1) {     // single segment: quadratic in t = m - mj
        const float C = 0.5f * s_cdt[jf];
        const float B = dtf * s_Vf[jf] - C;
        const float A = s_Pf[jf];
        const int mj = s_m[jf];
        for (long long i = ii; i < i1; i += blockDim.x) {
            const float t0 = (float)(int)(2 * i - mj), t1 = t0 + 1.0f;
            const float mf0 = (float)(2 * i), mf1 = mf0 + 1.0f;
            float4 o;
            o.x = fmaf(mf0, cxf, pxf);
            o.z = fmaf(mf1, cxf, pxf);
            o.y = fmaf(t0, fmaf(t0, C, B), A);
            o.w = fmaf(t1, fmaf(t1, C, B), A);
            nt_store(&out[i], o);
        }
    } else if (mode == 2) {     // single run: linear in t
        const float A = r_pf[rf], Bv = r_if[rf];
        const int rn0 = r_n[rf];
        for (long long i = ii; i < i1; i += blockDim.x) {
            const float t0 = (float)(int)(2 * i - rn0), t1 = t0 + 1.0f;
            const float mf0 = (float)(2 * i), mf1 = mf0 + 1.0f;
            float4 o;
            o.x = fmaf(mf0, cxf, pxf);
            o.z = fmaf(mf1, cxf, pxf);
            o.y = fmaf(t0, Bv, A);
            o.w = fmaf(t1, Bv, A);
            nt_store(&out[i], o);
        }
    } else {                    // general (boundary blocks)
        int j = 0, r = 0;
        if (nseg > 0) {
            const int t0 = (int)(2 * ii);
            int lo = 0, hi = nseg - 1;
            while (lo < hi) { int mid = (lo + hi + 1) >> 1; if (s_m[mid] <= t0) lo = mid; else hi = mid - 1; }
            j = lo;
            if (nrun > 0) {
                int rlo = 0, rhi = nrun - 1;
                while (rlo < rhi) { int mid = (rlo + rhi + 1) >> 1; if (r_n[mid] <= t0) rlo = mid; else rhi = mid - 1; }
                r = rlo;
            }
        }
        for (long long i = ii; i < i1; i += blockDim.x) {
            const long long m0 = 2 * i, m1 = m0 + 1;
            const float mf0 = (float)m0, mf1 = (float)m1;
            float4 o;
            o.x = fmaf(mf0, cxf, pxf);
            o.z = fmaf(mf1, cxf, pxf);
            const int t0 = (int)m0;
            if (m1 < NPOLY) {
                o.y = pyf + dtf * (mf0 * vyf) + q2f * (mf0 * (mf0 - 1.0f) * 0.5f);
                o.w = pyf + dtf * (mf1 * vyf) + q2f * (mf1 * (mf1 - 1.0f) * 0.5f);
            } else if (m1 < NS || nrun <= 0) {
                while (s_m[j + 1] <= t0) ++j;
                float t = (float)(int)(m0 - s_m[j]);
                o.y = s_Pf[j] + dtf * (t * s_Vf[j]) + s_cdt[j] * (t * (t - 1.0f) * 0.5f);
                const int j1 = (s_m[j + 1] <= (int)m1) ? j + 1 : j;
                t = (float)(int)(m1 - s_m[j1]);
                o.w = s_Pf[j1] + dtf * (t * s_Vf[j1]) + s_cdt[j1] * (t * (t - 1.0f) * 0.5f);
            } else {
                while (r + 1 < nrun && r_n[r + 1] <= t0) ++r;
                o.y = r_pf[r] + (float)(int)(m0 - r_n[r]) * r_if[r];
                const int r1 = (r + 1 < nrun && r_n[r + 1] <= (int)m1) ? r + 1 : r;
                o.w = r_pf[r1] + (float)(int)(m1 - r_n[r1]) * r_if[r1];
            }
            nt_store(&out[i], o);
        }
    }
}

extern "C" void kernel_launch(void* const* d_in, const int* in_sizes, int n_in,
                              void* d_out, int out_size, void* d_ws, size_t ws_size,
                              hipStream_t stream) {
    // Inputs: [0] ball_mass (unused), [1] initial_position[2], [2] initial_velocity[2].
    const float* pos0 = (const float*)d_in[1];
    const float* vel0 = (const float*)d_in[2];

    // Workspace layout (doubles first for alignment).
    char* base = (char*)d_ws;
    size_t off = 64;
    int* counts = (int*)base;
    double* g_V  = (double*)(base + off); off += (size_t)SEGCAP * 8;
    double* g_c  = (double*)(base + off); off += (size_t)SEGCAP * 8;
    double* g_P  = (double*)(base + off); off += (size_t)SEGCAP * 8;
    double* g_rp = (double*)(base + off); off += (size_t)RUNCAP * 8;
    double* g_ri = (double*)(base + off); off += (size_t)RUNCAP * 8;
    int* g_m  = (int*)(base + off); off += ((size_t)(SEGCAP + 1) * 4 + 7) & ~(size_t)7;
    int* g_rn = (int*)(base + off);

    prep<<<1, 64, 0, stream>>>(pos0, vel0, counts, g_m, g_V, g_c, g_P,
                               g_rn, g_rp, g_ri);

    const long long npairs = (long long)out_size / 4;  // 5,000,000 float4s
    fill<<<1024, 256, 0, stream>>>(pos0, vel0, counts, g_m, g_V, g_c, g_P,
                                   g_rn, g_rp, g_ri, (float4*)d_out, npairs);
}

// Round 22
// 34.934 us; speedup vs baseline: 1.3142x; 1.3142x over previous
//
#include <hip/hip_runtime.h>
#include <stdint.h>

// Reference: pos += fl32(vel*dt); vel += fl32(fl32(-9.81)*fl32(0.01)); record pos.
// Exact emulation of the f32 scan via piecewise-constant-increment runs.
// r22 = r20 fused with the serial chain de-latency-fied (r21 measured it at
// ~24-28us, ~760cy/link):
//  (a) wave-uniform chain, ONE ballot picks T (monotone exact condition;
//      undershoot only splits a link; boundary steps become automatic 1-step
//      links when the ballot is empty) — replaces ~200cy serial fixups;
//  (b) deferred P: chain records (m,V,c); dP terms computed by all 256
//      threads in parallel + tid0 prefix (removes 5 f64 ops/link from chain);
//  (c) NPOLY 1e6 -> 4e6: poly drift ~n^2 through r1's 1.07e9@1e7 => ~1.7e8
//      at 4e6 (< late-region 4.03e8); 40% of blocks skip prep and write early.

static constexpr long long NSTEPS = 10000000LL;  // output rows
static constexpr long long NPOLY  = 4000000LL;   // polynomial cutover (even)
static constexpr long long NS     = 8000000LL;   // model/run cutover (even)
static constexpr long long KDIR   = 64;          // direct f32 steps
static constexpr int SEGCAP = 384;
static constexpr int RUNCAP = 96;

typedef float f4_native __attribute__((ext_vector_type(4)));

__device__ __forceinline__ bool same_binade_f32(float a, float b) {
    return (((__float_as_uint(a) ^ __float_as_uint(b)) & 0xFF800000u) == 0u);
}
__device__ __forceinline__ unsigned expfield(float v) {
    return (__float_as_uint(v) >> 23) & 0xFFu;
}
__device__ __forceinline__ float pow2f(int e) {
    return __uint_as_float((unsigned)(e + 127) << 23);
}
__device__ __forceinline__ double pow2d(int e) {
    return __longlong_as_double(((long long)(e + 1023)) << 52);
}
__device__ __forceinline__ void nt_store(float4* p, float4 v) {
    f4_native nv;
    nv.x = v.x; nv.y = v.y; nv.z = v.z; nv.w = v.w;
    __builtin_nontemporal_store(nv, (f4_native*)p);
}

__global__ __launch_bounds__(256, 4) void fused(
        const float* __restrict__ pos0, const float* __restrict__ vel0,
        float4* __restrict__ out, long long npairs)
{
    __shared__ int    s_m[SEGCAP + 1];
    __shared__ double s_V[SEGCAP], s_c[SEGCAP], s_P[SEGCAP], s_dP[SEGCAP];
    __shared__ float  s_Vf[SEGCAP], s_cdt[SEGCAP], s_Pf[SEGCAP];
    __shared__ int    r_n[RUNCAP];
    __shared__ double r_p[RUNCAP], r_i[RUNCAP];
    __shared__ float  r_pf[RUNCAP], r_if[RUNCAP];
    __shared__ int    s_nseg, s_bad, s_nrun;
    __shared__ long long s_mstop;
    __shared__ double s_v64, s_p64;

    const int tid  = threadIdx.x;
    const int lane = tid & 63;
    const int wv   = tid >> 6;

    const long long per = (npairs + (long long)gridDim.x - 1) / (long long)gridDim.x;
    const long long i0 = (long long)blockIdx.x * per;
    long long i1 = i0 + per; if (i1 > npairs) i1 = npairs;
    if (i0 >= npairs) return;
    const long long row0 = 2 * i0;
    const long long row1 = 2 * i1;
    const long long mstop = row1 < NSTEPS ? row1 : NSTEPS;

    const float dtf  = 0.01f;
    const float gdtf = __fmul_rn(-9.81f, dtf);
    const double dtd = (double)dtf, gcd = (double)gdtf, gdtd = gcd;
    const double p0y = (double)pos0[1], v0y = (double)vel0[1];

    // Unique tie binade: gc = -M*2^E (M odd); tie iff k = E+25.
    int k_tie;
    {
        unsigned gbits = __float_as_uint(gdtf);
        unsigned mant = (gbits & 0x7FFFFFu) | 0x800000u;
        int tz = __ffs((int)mant) - 1;
        int E = (int)((gbits >> 23) & 0xFFu) - 127 - 23 + tz;
        k_tie = E + 25;
    }

    if (tid == 0) { s_nseg = 0; s_nrun = 0; s_mstop = 0; s_bad = 0; }
    __syncthreads();

    // ===== Phase A (wave 0, WAVE-UNIFORM): direct-64 + ballot-T staircase ===
    if (wv == 0 && row1 > NPOLY) {
        double V = v0y, P = p0y;
        for (int t = 0; t < (int)KDIR; ++t) {      // exact by definition
            const float vf = (float)V;
            P += dtd * V;
            V = (double)__fadd_rn(vf, gdtf);
        }
        if (lane == 0) { s_v64 = V; s_p64 = P; }

        bool bad = false;
        long long m = KDIR;
        int nseg = 0;
        while (m < mstop && nseg < SEGCAP - 2) {
            const float vf = (float)V;
            const unsigned ef = expfield(vf);
            bad = bad | ((double)vf != V) | !(vf < 0.0f) | (ef == 0u) | (ef == 0xFFu);
            if (bad) break;                         // wave-uniform
            const int k = (int)ef - 126;            // |V| in [2^(k-1), 2^k)
            const float vn1 = __fadd_rn(vf, gdtf);
            const double c = (double)vn1 - V;       // exact 1-step increment
            if (!(c < 0.0)) { bad = true; break; }
            const long long rem = mstop - m;

            long long T = 1;                        // 1-step always exact
            if (k != k_tie) {
                const double inv_ulp = pow2d(24 - k);
                const double g  = -V * inv_ulp;     // exact integer [2^23,2^24)
                const double q  = -gcd * inv_ulp;   // exact dyadic, > 0
                const double cg = -c * inv_ulp;     // exact integer >= 1
                const double lim = 16777216.0;
                float t0f = __fdividef((float)(lim - g - q), (float)cg);
                const long long Th = (long long)t0f;
                // One ballot: highest Tc in [Th-31, Th+32] with the exact
                // monotone stay-condition. Empty => T=1 (boundary step).
                const long long Tc = Th - 31 + (long long)lane;
                const bool valid = (Tc >= 1) && (Tc <= rem)
                                && (g + (double)(Tc - 1) * cg + q < lim);
                const unsigned long long msk = __ballot(valid);
                if (msk) T = Th - 31 + (long long)(63 - __clzll(msk));
                else     T = (Th - 31 > rem) ? rem : 1;
                if (T < 1) T = 1;
                if (T > rem) T = rem;
            }
            if (lane == 0) { s_m[nseg] = (int)m; s_V[nseg] = V; s_c[nseg] = c; }
            ++nseg;
            V += (double)T * c;                     // exact dyadics
            m += T;
        }
        bad = bad | (m < mstop);
        if (lane == 0) {
            s_bad = bad ? 1 : 0;
            s_nseg = nseg;
            s_mstop = m;
            s_m[nseg] = 0x7fffffff;                 // sentinel
        }
    }
    __syncthreads();

    // ===== Phase B: fallback — proven ballot staircase (inline P) ===========
    if (wv == 0 && s_bad && row1 > NPOLY) {
        double V = s_v64, P = s_p64;
        long long m = KDIR;
        int nseg = 0;
        while (m < mstop && nseg < SEGCAP) {
            const float vf  = (float)V;
            const float vn1 = __fadd_rn(vf, gdtf);
            const double c  = (double)vn1 - V;
            const long long rem = mstop - m;
            long long Lb = rem;
            const float cf = (float)c;
            const unsigned ef = expfield(vf);
            if (vf == 0.0f || ef == 0u) {
                Lb = 64;
            } else if (cf != 0.0f) {
                const int k = (int)ef - 126;
                float s = vf < 0.0f ? -1.0f : 1.0f;
                float B = ((vf < 0.0f) == (cf < 0.0f)) ? s * pow2f(k) : s * pow2f(k - 1);
                float r = __fdividef(B - vf, cf);
                if (r >= 0.0f && r < 4.0e9f) Lb = (long long)r + 1;
            }
            long long Lhi = Lb + 2;
            if (Lhi > rem) Lhi = rem;
            if (Lhi < 1) Lhi = 1;

            long long L = 1;
            {
                const long long candL = Lhi - 63 + (long long)lane;
                bool valid = false;
                if (candL >= 1) {
                    const double ve = V + (double)(candL - 1) * c;
                    const float vef = (float)ve;
                    const float vn2 = __fadd_rn(vef, gdtf);
                    valid = ((double)vef == ve)
                         && same_binade_f32(vef, vf)
                         && ((double)vn2 - ve == c);
                }
                const unsigned long long msk = __ballot(valid);
                if (msk) L = Lhi - 63 + (long long)(63 - __clzll(msk));
            }
            if (L < 1) L = 1;
            if (L > rem) L = rem;

            if (lane == 0) { s_m[nseg] = (int)m; s_V[nseg] = V; s_c[nseg] = c; s_P[nseg] = P; }
            ++nseg;
            P += dtd * ((double)L * V + c * ((double)L * (double)(L - 1) * 0.5));
            V += (double)L * c;
            m += L;
        }
        if (lane == 0) { s_nseg = nseg; s_mstop = m; s_m[nseg] = 0x7fffffff; }
    }
    __syncthreads();

    // ===== Phase P: deferred P (parallel terms + tid0 prefix) ===============
    if (!s_bad && row1 > NPOLY && s_nseg > 0) {
        const int nseg = s_nseg;
        for (int j = tid; j < nseg; j += 256) {
            const long long mj = s_m[j];
            const long long me = (j + 1 < nseg) ? (long long)s_m[j + 1] : s_mstop;
            const double len = (double)(me - mj);
            s_dP[j] = dtd * (len * s_V[j] + s_c[j] * (len * (len - 1.0) * 0.5));
        }
        __syncthreads();
        if (tid == 0) {
            double P = s_p64;
            for (int j = 0; j < nseg; ++j) { s_P[j] = P; P += s_dP[j]; }
        }
    }
    __syncthreads();

    // ===== Phase D (wave 0): pos run-chain from NS (single-window ballots) ==
    if (wv == 0 && row1 > NS && s_mstop >= NS && s_nseg > 0) {
        const int nseg = s_nseg;
        const long long mbuilt = s_mstop;
        int lo = 0, hi = nseg - 1;
        while (lo < hi) { int mid = (lo + hi + 1) >> 1;
                          if ((long long)s_m[mid] <= NS) lo = mid; else hi = mid - 1; }
        int jj = lo;
        const double t0 = (double)(NS - s_m[jj]);
        double vel = s_V[jj] + t0 * s_c[jj];
        double P2  = s_P[jj] + dtd * (t0 * s_V[jj] + s_c[jj] * (t0 * (t0 - 1.0) * 0.5));
        double pos = (double)(float)P2;
        long long n = NS;
        int nrun = 0;
        long long nend = (row1 < NSTEPS - 1) ? row1 : (NSTEPS - 1);
        if (nend > mbuilt) nend = mbuilt;
        while (n < nend && nrun < RUNCAP) {
            while (s_m[jj + 1] <= (int)n) ++jj;
            const double cv = s_c[jj];
            long long Lcap = (long long)s_m[jj + 1] - n;
            if (Lcap > mbuilt - n) Lcap = mbuilt - n;
            const long long rem = (NSTEPS - 1) - n;
            if (Lcap > rem) Lcap = rem;

            const float pf = (float)pos;
            const float vf2 = (float)vel;
            const float dstep = __fmul_rn(vf2, dtf);
            const float pn1 = __fadd_rn(pf, dstep);
            const double inc = (double)pn1 - pos;

            long long La = Lcap, Lc = Lcap;
            const float incf = (float)inc;
            const unsigned efp = expfield(pf);
            if (pf == 0.0f || efp == 0u) {
                La = 64;
            } else if (incf != 0.0f) {
                const int k = (int)efp - 126;
                float s = pf < 0.0f ? -1.0f : 1.0f;
                float B = ((pf < 0.0f) == (incf < 0.0f)) ? s * pow2f(k) : s * pow2f(k - 1);
                float r = __fdividef(B - pf, incf);
                if (r >= 0.0f && r < 4.0e9f) { La = (long long)r - 1; if (La < 0) La = 0; }
            }
            const double dd = cv * dtd;
            if (dd != 0.0 && pf != 0.0f && efp != 0u) {
                const int k = (int)efp - 126;
                if (k - 24 > -126) {
                    const float ulpf = pow2f(k - 24);
                    const double d0 = (double)dstep;
                    const double T = inc + (dd < 0.0 ? -0.5 : 0.5) * (double)ulpf;
                    float r = __fdividef((float)(T - d0), (float)dd);
                    if (r >= 0.0f && r < 4.0e9f) { Lc = (long long)r + 2; if (Lc < 1) Lc = 1; }
                }
            }
            long long Lhi = La < Lc ? La : Lc;
            Lhi += 3;
            if (Lhi > Lcap) Lhi = Lcap;
            if (Lhi < 1) Lhi = 1;

            long long L = 1;
            {
                const long long candL = Lhi - 63 + (long long)lane;
                bool valid = false;
                if (candL >= 1) {
                    const double pe = pos + (double)(candL - 1) * inc;
                    const double ve = vel + (double)(candL - 1) * cv;
                    const float pef = (float)pe;
                    const float vef = (float)ve;
                    const float d2  = __fmul_rn(vef, dtf);
                    const float pn2 = __fadd_rn(pef, d2);
                    valid = ((double)pef == pe)
                         && same_binade_f32(pef, pf)
                         && ((double)vef == ve)
                         && ((double)pn2 - pe == inc);
                }
                const unsigned long long msk = __ballot(valid);
                if (msk) L = Lhi - 63 + (long long)(63 - __clzll(msk));
            }
            if (L < 1) L = 1;
            if (L > Lcap) L = Lcap;
            if (L < 1) L = 1;

            if (lane == 0) { r_n[nrun] = (int)n; r_p[nrun] = pos; r_i[nrun] = inc; }
            ++nrun;
            pos += (double)L * inc;
            vel += (double)L * cv;
            n += L;
        }
        if (lane == 0) s_nrun = nrun;
    }
    __syncthreads();

    // ===== f32 mirror tables ================================================
    {
        const int nseg = s_nseg, nrun = s_nrun;
        for (int i = tid; i < nseg; i += 256) {
            s_Vf[i]  = (float)s_V[i];
            s_cdt[i] = (float)(dtd * s_c[i]);
            s_Pf[i]  = (float)s_P[i];
        }
        for (int i = tid; i < nrun; i += 256) {
            r_pf[i] = (float)r_p[i];
            r_if[i] = (float)r_i[i];
        }
    }
    __syncthreads();

    // ===== Fill with per-block fast paths (nontemporal stores) ==============
    const int nseg = s_nseg;
    const int nrun = s_nrun;
    const float pxf = pos0[0];
    const float cxf = __fmul_rn(vel0[0], dtf);
    const float pyf = (float)p0y;
    const float vyf = (float)v0y;
    const float q2f = (float)(dtd * gdtd);       // dt*gc

    const long long ii = i0 + tid;
    if (ii >= i1) return;

    // Classify block: 0 poly, 1 single-segment, 2 single-run, 3 general.
    int mode = 3, jf = 0, rf = 0;
    if (row1 <= NPOLY) {
        mode = 0;
    } else if (row0 >= NS && nrun > 0) {
        int rlo = 0, rhi = nrun - 1;
        const int t0 = (int)row0;
        while (rlo < rhi) { int mid = (rlo + rhi + 1) >> 1; if (r_n[mid] <= t0) rlo = mid; else rhi = mid - 1; }
        rf = rlo;
        if (rf + 1 >= nrun || (long long)r_n[rf + 1] >= row1) mode = 2;
    } else if (row0 >= NPOLY && row1 <= NS && nseg > 0) {
        int lo = 0, hi = nseg - 1;
        const int t0 = (int)row0;
        while (lo < hi) { int mid = (lo + hi + 1) >> 1; if (s_m[mid] <= t0) lo = mid; else hi = mid - 1; }
        jf = lo;
        if ((long long)s_m[jf + 1] >= row1) mode = 1;
    }

    if (mode == 0) {            // y = A + B*m + C*m^2 (registers only)
        const float C = 0.5f * q2f;
        const float B = dtf * vyf - C;
        const float A = pyf;
        for (long long i = ii; i < i1; i += blockDim.x) {
            const float mf0 = (float)(2 * i), mf1 = mf0 + 1.0f;
            float4 o;
            o.x = fmaf(mf0, cxf, pxf);
            o.z = fmaf(mf1, cxf, pxf);
            o.y = fmaf(mf0, fmaf(mf0, C, B), A);
            o.w = fmaf(mf1, fmaf(mf1, C, B), A);
            nt_store(&out[i], o);
        }
    } else if (mode == 1) {     // single segment: quadratic in t = m - mj
        const float C = 0.5f * s_cdt[jf];
        const float B = dtf * s_Vf[jf] - C;
        const float A = s_Pf[jf];
        const int mj = s_m[jf];
        for (long long i = ii; i < i1; i += blockDim.x) {
            const float t0 = (float)(int)(2 * i - mj), t1 = t0 + 1.0f;
            const float mf0 = (float)(2 * i), mf1 = mf0 + 1.0f;
            float4 o;
            o.x = fmaf(mf0, cxf, pxf);
            o.z = fmaf(mf1, cxf, pxf);
            o.y = fmaf(t0, fmaf(t0, C, B), A);
            o.w = fmaf(t1, fmaf(t1, C, B), A);
            nt_store(&out[i], o);
        }
    } else if (mode == 2) {     // single run: linear in t
        const float A = r_pf[rf], Bv = r_if[rf];
        const int rn0 = r_n[rf];
        for (long long i = ii; i < i1; i += blockDim.x) {
            const float t0 = (float)(int)(2 * i - rn0), t1 = t0 + 1.0f;
            const float mf0 = (float)(2 * i), mf1 = mf0 + 1.0f;
            float4 o;
            o.x = fmaf(mf0, cxf, pxf);
            o.z = fmaf(mf1, cxf, pxf);
            o.y = fmaf(t0, Bv, A);
            o.w = fmaf(t1, Bv, A);
            nt_store(&out[i], o);
        }
    } else {                    // general (boundary blocks)
        int j = 0, r = 0;
        if (nseg > 0) {
            const int t0 = (int)(2 * ii);
            int lo = 0, hi = nseg - 1;
            while (lo < hi) { int mid = (lo + hi + 1) >> 1; if (s_m[mid] <= t0) lo = mid; else hi = mid - 1; }
            j = lo;
            if (nrun > 0) {
                int rlo = 0, rhi = nrun - 1;
                while (rlo < rhi) { int mid = (rlo + rhi + 1) >> 1; if (r_n[mid] <= t0) rlo = mid; else rhi = mid - 1; }
                r = rlo;
            }
        }
        for (long long i = ii; i < i1; i += blockDim.x) {
            const long long m0 = 2 * i, m1 = m0 + 1;
            const float mf0 = (float)m0, mf1 = (float)m1;
            float4 o;
            o.x = fmaf(mf0, cxf, pxf);
            o.z = fmaf(mf1, cxf, pxf);
            const int t0 = (int)m0;
            if (m1 < NPOLY) {
                const float C = 0.5f * q2f;
                const float B = dtf * vyf - C;
                o.y = fmaf(mf0, fmaf(mf0, C, B), pyf);
                o.w = fmaf(mf1, fmaf(mf1, C, B), pyf);
            } else if (m1 < NS || nrun <= 0) {
                while (s_m[j + 1] <= t0) ++j;
                float t = (float)(int)(m0 - s_m[j]);
                o.y = s_Pf[j] + dtf * (t * s_Vf[j]) + s_cdt[j] * (t * (t - 1.0f) * 0.5f);
                const int j1 = (s_m[j + 1] <= (int)m1) ? j + 1 : j;
                t = (float)(int)(m1 - s_m[j1]);
                o.w = s_Pf[j1] + dtf * (t * s_Vf[j1]) + s_cdt[j1] * (t * (t - 1.0f) * 0.5f);
            } else {
                while (r + 1 < nrun && r_n[r + 1] <= t0) ++r;
                o.y = r_pf[r] + (float)(int)(m0 - r_n[r]) * r_if[r];
                const int r1 = (r + 1 < nrun && r_n[r + 1] <= (int)m1) ? r + 1 : r;
                o.w = r_pf[r1] + (float)(int)(m1 - r_n[r1]) * r_if[r1];
            }
            nt_store(&out[i], o);
        }
    }
}

extern "C" void kernel_launch(void* const* d_in, const int* in_sizes, int n_in,
                              void* d_out, int out_size, void* d_ws, size_t ws_size,
                              hipStream_t stream) {
    // Inputs: [0] ball_mass (unused), [1] initial_position[2], [2] initial_velocity[2].
    const float* pos0 = (const float*)d_in[1];
    const float* vel0 = (const float*)d_in[2];

    const long long npairs = (long long)out_size / 4;  // 5,000,000 float4s
    fused<<<1024, 256, 0, stream>>>(pos0, vel0, (float4*)d_out, npairs);
}